// Round 27
// baseline (39.468 us; speedup 1.0000x reference)
//
#include <hip/hip_runtime.h>
#include <hip/hip_fp16.h>
#include <math.h>

// SSIM loss — champion r26 (38.5us, absmax 0.0: r19 structure + XCD swizzle)
// + per-wave-balanced staging assignment.
// r26's staging gave waves {128,128,100,64} items; the single barrier waits
// for the slowest wave (128). Balanced: every wave stages exactly 105 items
// (it = wid*105 + lane, and +64 for lane<41) -> 18% less barrier-critical
// staging work. Everything else identical:
//   ph1: write prefetched {x,y} regs as f16 planes into buf[g&1];
//        issue next tile's global loads (in flight across raw s_barrier).
//   ONE barrier (lgkmcnt(0)+s_barrier+sched_barrier(0)).
//   compute: 6 ds_read_b128 -> s,p packed f16 -> 12 banded K=32 H-MFMAs
//     (Bh[j]=g[8am+j-cl-3]) -> register-chained 16x16x16 V-MFMAs
//     (Av1[j]=g[4am+j-cl], Av2[j]=g[4am+j+16-cl]) -> SSIM on 8 reg px.
//   T1 XCD swizzle: wg=(orig&7)*128+(orig>>3) (bijective, 1024%8==0);
//   each XCD covers 6 whole planes -> all halo re-reads are local-L2 hits
//   (r26: FETCH 87->77MB, dur 40.3->38.5).
// Session ledger: (256,4) launch bounds mandatory (unified VGPR/AGPR spill
// cliff, r15/r16/r17); no dyn-indexed/shuffled frag arrays (r21); 4/CU
// grid (r18); coalesced staging (r13); barriers 3->2->1, pipelining,
// fused V-MFMA, wave-private variants: all flat/worse.

#define HH 512
#define WW 512
#define HW (HH*WW)
#define NPLANES 48
#define G_TILES 6
#define NBLOCKS 1024           // 6144 tiles / 6

typedef _Float16 f16x8 __attribute__((ext_vector_type(8)));
typedef _Float16 f16x4 __attribute__((ext_vector_type(4)));
typedef float f32x4 __attribute__((ext_vector_type(4)));

#define RAW_STRIDE 208         // bytes per staged row (104 f16; 80 used)
#define RAW_PLANE  9984        // 48*208; x at 0, y at RAW_PLANE
#define BUF_B      19968       // one buffer: 2 planes
#define LDS_TOTAL  39936       // 2 buffers (ping-pong)

struct WParam { float A, B; };

__global__ void ssim_init_out(float* out) { out[0] = 1.0f; }

__device__ __forceinline__ void barrier_nodrain() {
    asm volatile("s_waitcnt lgkmcnt(0)" ::: "memory");
    __builtin_amdgcn_s_barrier();
    __builtin_amdgcn_sched_barrier(0);
}

__global__ __launch_bounds__(256, 4)
void ssim_mfma(const float* __restrict__ img, const float* __restrict__ tgt,
               float* __restrict__ out, WParam wp) {
    __shared__ alignas(16) char lds[LDS_TOTAL];
    __shared__ float wsum[4];

    const int tid  = threadIdx.x;
    const int wid  = tid >> 6;
    const int lane = tid & 63;
    const int cl   = lane & 15;
    const int am   = lane >> 4;

    // balanced staging:每wave exactly 105 of 420 items (105 = 64 + 41)
    const int it0 = wid * 105 + lane;
    const int it1 = it0 + 64;
    const int ir0 = it0 / 10, ig0 = it0 - 10 * ir0;
    const int ir1 = it1 / 10, ig1 = it1 - 10 * ir1;
    const bool has1 = (lane < 41);

    float4 Xa[2], Xb[2], Ya[2], Yb[2];

    auto load_tile = [&](int tlin) {
        const int p   = tlin >> 7;
        const int rem = tlin & 127;
        const int R0  = (rem >> 3) * 32;
        const int C0  = (rem & 7) * 64;
        const float* ip = img + (size_t)p * HW;
        const float* tp = tgt + (size_t)p * HW;
        #pragma unroll
        for (int s = 0; s < 2; ++s) {
            if (s == 1 && !has1) break;
            int r   = s ? ir1 : ir0;
            int grp = s ? ig1 : ig0;
            int gr  = R0 - 5 + r;
            int gc0 = C0 - 8 + grp * 8;
            float4 xa = make_float4(0.f,0.f,0.f,0.f), xb = xa, ya = xa, yb = xa;
            if ((unsigned)gr < (unsigned)HH) {
                const float* xr = ip + (size_t)gr * WW;
                const float* yr = tp + (size_t)gr * WW;
                if ((unsigned)gc0 <= (unsigned)(WW - 4)) {
                    xa = *(const float4*)(xr + gc0);
                    ya = *(const float4*)(yr + gc0);
                }
                if ((unsigned)(gc0 + 4) <= (unsigned)(WW - 4)) {
                    xb = *(const float4*)(xr + gc0 + 4);
                    yb = *(const float4*)(yr + gc0 + 4);
                }
            }
            Xa[s] = xa; Xb[s] = xb; Ya[s] = ya; Yb[s] = yb;
        }
    };

    auto write_tile = [&](char* buf) {
        #pragma unroll
        for (int s = 0; s < 2; ++s) {
            if (s == 1 && !has1) break;
            int r   = s ? ir1 : ir0;
            int grp = s ? ig1 : ig0;
            f16x8 hx, hy;
            hx[0]=(_Float16)Xa[s].x; hx[1]=(_Float16)Xa[s].y;
            hx[2]=(_Float16)Xa[s].z; hx[3]=(_Float16)Xa[s].w;
            hx[4]=(_Float16)Xb[s].x; hx[5]=(_Float16)Xb[s].y;
            hx[6]=(_Float16)Xb[s].z; hx[7]=(_Float16)Xb[s].w;
            hy[0]=(_Float16)Ya[s].x; hy[1]=(_Float16)Ya[s].y;
            hy[2]=(_Float16)Ya[s].z; hy[3]=(_Float16)Ya[s].w;
            hy[4]=(_Float16)Yb[s].x; hy[5]=(_Float16)Yb[s].y;
            hy[6]=(_Float16)Yb[s].z; hy[7]=(_Float16)Yb[s].w;
            char* base = buf + r * RAW_STRIDE + grp * 16;
            *(f16x8*)(base + 0*RAW_PLANE) = hx;
            *(f16x8*)(base + 1*RAW_PLANE) = hy;
        }
    };

    // T1: bijective XCD swizzle — each XCD covers 6 whole planes.
    const int orig = blockIdx.x;
    const int wg   = (orig & 7) * (NBLOCKS / 8) + (orig >> 3);
    const int base_t = wg * G_TILES;
    load_tile(base_t);                 // prologue prefetch (overlaps init)

    // ---- one-time LDS zero-init, BOTH buffers (pad regions stay zero) ----
    for (int i = tid; i < LDS_TOTAL / 4; i += 256)
        ((float*)lds)[i] = 0.f;

    // ---- per-lane weight fragments ----
    f16x8 Bh;
    #pragma unroll
    for (int j = 0; j < 8; ++j) {
        int ih = 8*am + j - cl - 3;
        float t = (float)(ih - 5);
        Bh[j] = ((unsigned)ih <= 10u) ? (_Float16)(wp.A * exp2f(-wp.B*t*t))
                                      : (_Float16)0.f;
    }
    f16x4 Av1, Av2;
    #pragma unroll
    for (int j = 0; j < 4; ++j) {
        int k = 4*am + j;
        int i1 = k - cl;
        float t1 = (float)(i1 - 5);
        Av1[j] = ((unsigned)i1 <= 10u) ? (_Float16)(wp.A * exp2f(-wp.B*t1*t1))
                                       : (_Float16)0.f;
        int i2 = k + 16 - cl;
        float t2 = (float)(i2 - 5);
        Av2[j] = ((unsigned)i2 <= 10u) ? (_Float16)(wp.A * exp2f(-wp.B*t2*t2))
                                       : (_Float16)0.f;
    }
    __syncthreads();

    const float C1 = 1e-4f, C2 = 9e-4f;
    float lsum = 0.f;

    for (int g = 0; g < G_TILES; ++g) {
        char* buf = lds + (g & 1) * BUF_B;

        // ---- phase 1: write prefetched tile to buf; issue next prefetch ----
        write_tile(buf);
        if (g + 1 < G_TILES) load_tile(base_t + g + 1);
        barrier_nodrain();             // the ONLY barrier in the loop

        // ---- compute: all-register H+V blur + SSIM (no LDS writes) ----
        {
            const int abase = cl * RAW_STRIDE + 32 * wid + am * 16;
            f16x8 hx3[3], hy3[3];
            #pragma unroll
            for (int mt = 0; mt < 3; ++mt) {
                hx3[mt] = *(const f16x8*)(buf + (16*mt) * RAW_STRIDE + abase);
                hy3[mt] = *(const f16x8*)(buf + RAW_PLANE + (16*mt) * RAW_STRIDE + abase);
            }

            f32x4 accv[4][2];
            #pragma unroll
            for (int q = 0; q < 4; ++q) {
                f32x4 Dh[3];
                #pragma unroll
                for (int mt = 0; mt < 3; ++mt) {
                    f16x8 A = (q == 0) ? hx3[mt]
                            : (q == 1) ? hy3[mt]
                            : (q == 2) ? (f16x8)(hx3[mt]*hx3[mt] + hy3[mt]*hy3[mt])
                                       : (f16x8)(hx3[mt]*hy3[mt]);
                    f32x4 zz = {0.f, 0.f, 0.f, 0.f};
                    Dh[mt] = __builtin_amdgcn_mfma_f32_16x16x32_f16(A, Bh, zz, 0, 0, 0);
                }
                #pragma unroll
                for (int mtv = 0; mtv < 2; ++mtv) {
                    f16x4 B1, B2;
                    #pragma unroll
                    for (int j = 0; j < 4; ++j) {
                        B1[j] = (_Float16)Dh[mtv][j];
                        B2[j] = (_Float16)Dh[mtv+1][j];
                    }
                    f32x4 zz = {0.f, 0.f, 0.f, 0.f};
                    f32x4 acc = __builtin_amdgcn_mfma_f32_16x16x16f16(Av2, B2, zz, 0, 0, 0);
                    accv[q][mtv] = __builtin_amdgcn_mfma_f32_16x16x16f16(Av1, B1, acc, 0, 0, 0);
                }
            }

            #pragma unroll
            for (int mtv = 0; mtv < 2; ++mtv) {
                #pragma unroll
                for (int j = 0; j < 4; ++j) {
                    float mu1 = accv[0][mtv][j], mu2 = accv[1][mtv][j];
                    float bss = accv[2][mtv][j], bxy = accv[3][mtv][j];
                    float mu1s = mu1*mu1, mu2s = mu2*mu2, mu12 = mu1*mu2;
                    float ssum = bss - mu1s - mu2s;
                    float s12  = bxy - mu12;
                    float num = (2.f*mu12 + C1) * (2.f*s12 + C2);
                    float den = (mu1s + mu2s + C1) * (ssum + C2);
                    lsum = fmaf(num, __builtin_amdgcn_rcpf(den), lsum);
                }
            }
        }
        // no trailing barrier: next iteration writes the OTHER buffer
    }

    // ---- block reduction + one atomic ----
    for (int off = 32; off > 0; off >>= 1)
        lsum += __shfl_down(lsum, off, 64);
    if (lane == 0) wsum[wid] = lsum;
    __syncthreads();
    if (tid == 0) {
        float bsum = wsum[0] + wsum[1] + wsum[2] + wsum[3];
        const float invN = 1.0f / (float)((size_t)NPLANES * HH * WW);
        atomicAdd(out, -bsum * invN);
    }
}

extern "C" void kernel_launch(void* const* d_in, const int* in_sizes, int n_in,
                              void* d_out, int out_size, void* d_ws, size_t ws_size,
                              hipStream_t stream) {
    const float* img = (const float*)d_in[0];
    const float* tgt = (const float*)d_in[1];
    float* out = (float*)d_out;

    // g[i] = exp(-(i-5)^2/4.5)/s = A * 2^(-B*(i-5)^2)
    double s = 0.0;
    for (int i = 0; i < 11; ++i) {
        double d = (double)(i - 5);
        s += exp(-(d * d) / 4.5);
    }
    WParam wp;
    wp.A = (float)(1.0 / s);
    wp.B = (float)(M_LOG2E / 4.5);

    ssim_init_out<<<1, 1, 0, stream>>>(out);
    ssim_mfma<<<NBLOCKS, 256, 0, stream>>>(img, tgt, out, wp);
}

// Round 28
// 38.604 us; speedup vs baseline: 1.0224x; 1.0224x over previous
//
#include <hip/hip_runtime.h>
#include <hip/hip_fp16.h>
#include <math.h>

// SSIM loss — FINAL champion (r26: 38.5us, absmax 0.0).
// r19 structure (double-buffered LDS ping-pong, 1 no-drain barrier/tile,
// banded K=32 H-MFMA + register-chained 16x16x16 V-MFMA, cross-tile register
// prefetch) + T1 bijective XCD-aware block swizzle.
// Per 64x32 tile:
//   ph1: write prefetched {x,y} regs as f16 planes into buf[g&1];
//        issue next tile's global loads (in flight across raw s_barrier).
//   ONE barrier (lgkmcnt(0)+s_barrier+sched_barrier(0)).
//   compute: 6 ds_read_b128 -> s,p packed f16 -> 12 banded K=32 H-MFMAs
//     (Bh[j]=g[8am+j-cl-3]) -> register-chained 16x16x16 V-MFMAs
//     (Av1[j]=g[4am+j-cl], Av2[j]=g[4am+j+16-cl]) -> SSIM on 8 reg px.
//   T1 swizzle wg=(orig&7)*128+(orig>>3) (bijective, 1024%8==0): each XCD
//   covers 6 whole planes -> halo re-reads are local-L2 hits
//   (FETCH 87->77MB, dur 40.3->38.5, r26).
// Session ledger (15 structural experiments; why this is the floor):
//  - (256,4) launch bounds mandatory: gfx950 unified VGPR/AGPR budget under
//    (256,6)/(256,8) splits to 40/32 arch regs -> 100-300MB scratch spill,
//    3x slowdown (r15/r16/r17, also r21's shufflevector variant).
//  - No shufflevector/dyn-indexing on fragment arrays (r21).
//  - Grid 1024 = 4/CU; 8/CU assigned regresses (r18: halo-reuse loss).
//  - Per-lane scattered global loads destroy coalescing (r13: 3.3x).
//  - Zero-barrier wave-private: 45-46us (r23/r24, ~16wg/CU cap + redundancy).
//  - Barriers 3->2->1, pipelined frag reads, fused V-MFMA, balanced staging
//    (r27): all flat/worse.
//  Plateau: ~4-5 waves/SIMD x ~3K-cyc per-tile dependency chain; no pipe
//  >35%; deeper ILP needs register budget that provably spills.

#define HH 512
#define WW 512
#define HW (HH*WW)
#define NPLANES 48
#define G_TILES 6
#define NBLOCKS 1024           // 6144 tiles / 6

typedef _Float16 f16x8 __attribute__((ext_vector_type(8)));
typedef _Float16 f16x4 __attribute__((ext_vector_type(4)));
typedef float f32x4 __attribute__((ext_vector_type(4)));

#define RAW_STRIDE 208         // bytes per staged row (104 f16; 80 used)
#define RAW_PLANE  9984        // 48*208; x at 0, y at RAW_PLANE
#define BUF_B      19968       // one buffer: 2 planes
#define LDS_TOTAL  39936       // 2 buffers (ping-pong)

struct WParam { float A, B; };

__global__ void ssim_init_out(float* out) { out[0] = 1.0f; }

__device__ __forceinline__ void barrier_nodrain() {
    asm volatile("s_waitcnt lgkmcnt(0)" ::: "memory");
    __builtin_amdgcn_s_barrier();
    __builtin_amdgcn_sched_barrier(0);
}

__global__ __launch_bounds__(256, 4)
void ssim_mfma(const float* __restrict__ img, const float* __restrict__ tgt,
               float* __restrict__ out, WParam wp) {
    __shared__ alignas(16) char lds[LDS_TOTAL];
    __shared__ float wsum[4];

    const int tid  = threadIdx.x;
    const int wid  = tid >> 6;
    const int lane = tid & 63;
    const int cl   = lane & 15;
    const int am   = lane >> 4;

    // fixed 2 staging items per thread (420 = 256 + 164)
    const int it0 = tid,       ir0 = it0 / 10, ig0 = it0 - 10 * ir0;
    const int it1 = tid + 256, ir1 = it1 / 10, ig1 = it1 - 10 * ir1;
    const bool has1 = (tid < 164);

    float4 Xa[2], Xb[2], Ya[2], Yb[2];

    auto load_tile = [&](int tlin) {
        const int p   = tlin >> 7;
        const int rem = tlin & 127;
        const int R0  = (rem >> 3) * 32;
        const int C0  = (rem & 7) * 64;
        const float* ip = img + (size_t)p * HW;
        const float* tp = tgt + (size_t)p * HW;
        #pragma unroll
        for (int s = 0; s < 2; ++s) {
            if (s == 1 && !has1) break;
            int r   = s ? ir1 : ir0;
            int grp = s ? ig1 : ig0;
            int gr  = R0 - 5 + r;
            int gc0 = C0 - 8 + grp * 8;
            float4 xa = make_float4(0.f,0.f,0.f,0.f), xb = xa, ya = xa, yb = xa;
            if ((unsigned)gr < (unsigned)HH) {
                const float* xr = ip + (size_t)gr * WW;
                const float* yr = tp + (size_t)gr * WW;
                if ((unsigned)gc0 <= (unsigned)(WW - 4)) {
                    xa = *(const float4*)(xr + gc0);
                    ya = *(const float4*)(yr + gc0);
                }
                if ((unsigned)(gc0 + 4) <= (unsigned)(WW - 4)) {
                    xb = *(const float4*)(xr + gc0 + 4);
                    yb = *(const float4*)(yr + gc0 + 4);
                }
            }
            Xa[s] = xa; Xb[s] = xb; Ya[s] = ya; Yb[s] = yb;
        }
    };

    auto write_tile = [&](char* buf) {
        #pragma unroll
        for (int s = 0; s < 2; ++s) {
            if (s == 1 && !has1) break;
            int r   = s ? ir1 : ir0;
            int grp = s ? ig1 : ig0;
            f16x8 hx, hy;
            hx[0]=(_Float16)Xa[s].x; hx[1]=(_Float16)Xa[s].y;
            hx[2]=(_Float16)Xa[s].z; hx[3]=(_Float16)Xa[s].w;
            hx[4]=(_Float16)Xb[s].x; hx[5]=(_Float16)Xb[s].y;
            hx[6]=(_Float16)Xb[s].z; hx[7]=(_Float16)Xb[s].w;
            hy[0]=(_Float16)Ya[s].x; hy[1]=(_Float16)Ya[s].y;
            hy[2]=(_Float16)Ya[s].z; hy[3]=(_Float16)Ya[s].w;
            hy[4]=(_Float16)Yb[s].x; hy[5]=(_Float16)Yb[s].y;
            hy[6]=(_Float16)Yb[s].z; hy[7]=(_Float16)Yb[s].w;
            char* base = buf + r * RAW_STRIDE + grp * 16;
            *(f16x8*)(base + 0*RAW_PLANE) = hx;
            *(f16x8*)(base + 1*RAW_PLANE) = hy;
        }
    };

    // T1: bijective XCD swizzle — same-XCD blocks get consecutive tile
    // ranges (6 whole planes per XCD) -> halo reuse in the local L2.
    const int orig = blockIdx.x;
    const int wg   = (orig & 7) * (NBLOCKS / 8) + (orig >> 3);
    const int base_t = wg * G_TILES;
    load_tile(base_t);                 // prologue prefetch (overlaps init)

    // ---- one-time LDS zero-init, BOTH buffers (pad regions stay zero) ----
    for (int i = tid; i < LDS_TOTAL / 4; i += 256)
        ((float*)lds)[i] = 0.f;

    // ---- per-lane weight fragments ----
    f16x8 Bh;
    #pragma unroll
    for (int j = 0; j < 8; ++j) {
        int ih = 8*am + j - cl - 3;
        float t = (float)(ih - 5);
        Bh[j] = ((unsigned)ih <= 10u) ? (_Float16)(wp.A * exp2f(-wp.B*t*t))
                                      : (_Float16)0.f;
    }
    f16x4 Av1, Av2;
    #pragma unroll
    for (int j = 0; j < 4; ++j) {
        int k = 4*am + j;
        int i1 = k - cl;
        float t1 = (float)(i1 - 5);
        Av1[j] = ((unsigned)i1 <= 10u) ? (_Float16)(wp.A * exp2f(-wp.B*t1*t1))
                                       : (_Float16)0.f;
        int i2 = k + 16 - cl;
        float t2 = (float)(i2 - 5);
        Av2[j] = ((unsigned)i2 <= 10u) ? (_Float16)(wp.A * exp2f(-wp.B*t2*t2))
                                       : (_Float16)0.f;
    }
    __syncthreads();

    const float C1 = 1e-4f, C2 = 9e-4f;
    float lsum = 0.f;

    for (int g = 0; g < G_TILES; ++g) {
        char* buf = lds + (g & 1) * BUF_B;

        // ---- phase 1: write prefetched tile to buf; issue next prefetch ----
        write_tile(buf);
        if (g + 1 < G_TILES) load_tile(base_t + g + 1);
        barrier_nodrain();             // the ONLY barrier in the loop

        // ---- compute: all-register H+V blur + SSIM (no LDS writes) ----
        {
            const int abase = cl * RAW_STRIDE + 32 * wid + am * 16;
            f16x8 hx3[3], hy3[3];
            #pragma unroll
            for (int mt = 0; mt < 3; ++mt) {
                hx3[mt] = *(const f16x8*)(buf + (16*mt) * RAW_STRIDE + abase);
                hy3[mt] = *(const f16x8*)(buf + RAW_PLANE + (16*mt) * RAW_STRIDE + abase);
            }

            f32x4 accv[4][2];
            #pragma unroll
            for (int q = 0; q < 4; ++q) {
                f32x4 Dh[3];
                #pragma unroll
                for (int mt = 0; mt < 3; ++mt) {
                    f16x8 A = (q == 0) ? hx3[mt]
                            : (q == 1) ? hy3[mt]
                            : (q == 2) ? (f16x8)(hx3[mt]*hx3[mt] + hy3[mt]*hy3[mt])
                                       : (f16x8)(hx3[mt]*hy3[mt]);
                    f32x4 zz = {0.f, 0.f, 0.f, 0.f};
                    Dh[mt] = __builtin_amdgcn_mfma_f32_16x16x32_f16(A, Bh, zz, 0, 0, 0);
                }
                #pragma unroll
                for (int mtv = 0; mtv < 2; ++mtv) {
                    f16x4 B1, B2;
                    #pragma unroll
                    for (int j = 0; j < 4; ++j) {
                        B1[j] = (_Float16)Dh[mtv][j];
                        B2[j] = (_Float16)Dh[mtv+1][j];
                    }
                    f32x4 zz = {0.f, 0.f, 0.f, 0.f};
                    f32x4 acc = __builtin_amdgcn_mfma_f32_16x16x16f16(Av2, B2, zz, 0, 0, 0);
                    accv[q][mtv] = __builtin_amdgcn_mfma_f32_16x16x16f16(Av1, B1, acc, 0, 0, 0);
                }
            }

            #pragma unroll
            for (int mtv = 0; mtv < 2; ++mtv) {
                #pragma unroll
                for (int j = 0; j < 4; ++j) {
                    float mu1 = accv[0][mtv][j], mu2 = accv[1][mtv][j];
                    float bss = accv[2][mtv][j], bxy = accv[3][mtv][j];
                    float mu1s = mu1*mu1, mu2s = mu2*mu2, mu12 = mu1*mu2;
                    float ssum = bss - mu1s - mu2s;
                    float s12  = bxy - mu12;
                    float num = (2.f*mu12 + C1) * (2.f*s12 + C2);
                    float den = (mu1s + mu2s + C1) * (ssum + C2);
                    lsum = fmaf(num, __builtin_amdgcn_rcpf(den), lsum);
                }
            }
        }
        // no trailing barrier: next iteration writes the OTHER buffer
    }

    // ---- block reduction + one atomic ----
    for (int off = 32; off > 0; off >>= 1)
        lsum += __shfl_down(lsum, off, 64);
    if (lane == 0) wsum[wid] = lsum;
    __syncthreads();
    if (tid == 0) {
        float bsum = wsum[0] + wsum[1] + wsum[2] + wsum[3];
        const float invN = 1.0f / (float)((size_t)NPLANES * HH * WW);
        atomicAdd(out, -bsum * invN);
    }
}

extern "C" void kernel_launch(void* const* d_in, const int* in_sizes, int n_in,
                              void* d_out, int out_size, void* d_ws, size_t ws_size,
                              hipStream_t stream) {
    const float* img = (const float*)d_in[0];
    const float* tgt = (const float*)d_in[1];
    float* out = (float*)d_out;

    // g[i] = exp(-(i-5)^2/4.5)/s = A * 2^(-B*(i-5)^2)
    double s = 0.0;
    for (int i = 0; i < 11; ++i) {
        double d = (double)(i - 5);
        s += exp(-(d * d) / 4.5);
    }
    WParam wp;
    wp.A = (float)(1.0 / s);
    wp.B = (float)(M_LOG2E / 4.5);

    ssim_init_out<<<1, 1, 0, stream>>>(out);
    ssim_mfma<<<NBLOCKS, 256, 0, stream>>>(img, tgt, out, wp);
}